// Round 7
// baseline (953.734 us; speedup 1.0000x reference)
//
#include <hip/hip_runtime.h>
#include <float.h>

#define DIN   768
#define DSAE  16384
#define K_    32
#define KTOT  2304
#define TD    12288   // 16*768
#define KSPLIT 8
#define KLEN   288
#define KC     32
#define NCH    9
#define SB     256
#define WSTR   36
#define NBLK   512

#define FMA4(ACC, S, A) { ACC.x += (S) * (A).x; ACC.y += (S) * (A).y; \
                          ACC.z += (S) * (A).z; ACC.w += (S) * (A).w; }

__device__ __forceinline__ int aidx(int k, int b) {   // XOR-swizzled A_lds layout
    return k * 32 + (b ^ ((k & 7) << 2));
}

struct EncSm { float Wt[SB * WSTR]; float A_lds[KLEN * 32]; };   // 73728 B
struct TkSm  { unsigned hist[256]; unsigned gsfx[65]; unsigned sfx[257];
               int sdelta; unsigned scnt; int l_idx[K_]; float l_val[K_]; int eq_min; };
struct DecSm { float sv[K_]; int si[K_]; float wsum[4]; };
union  MegaSm { EncSm e; TkSm t; DecSm d; };

// all NBLK blocks are co-resident (512 = 256 CU x 2 via LDS+launch_bounds),
// so a device-scope sense barrier is safe without cooperative launch.
__device__ __forceinline__ void grid_barrier(unsigned* cnt, unsigned* gen) {
    __syncthreads();
    if (threadIdx.x == 0) {
        __threadfence();
        unsigned g = __hip_atomic_load(gen, __ATOMIC_RELAXED, __HIP_MEMORY_SCOPE_AGENT);
        unsigned a = __hip_atomic_fetch_add(cnt, 1u, __ATOMIC_ACQ_REL,
                                            __HIP_MEMORY_SCOPE_AGENT) + 1u;
        if (a == NBLK) {
            __hip_atomic_store(cnt, 0u, __ATOMIC_RELAXED, __HIP_MEMORY_SCOPE_AGENT);
            __hip_atomic_fetch_add(gen, 1u, __ATOMIC_ACQ_REL, __HIP_MEMORY_SCOPE_AGENT);
        } else {
            while (__hip_atomic_load(gen, __ATOMIC_ACQUIRE,
                                     __HIP_MEMORY_SCOPE_AGENT) == g)
                __builtin_amdgcn_s_sleep(2);
        }
        __threadfence();
    }
    __syncthreads();
}

__global__ __launch_bounds__(256, 2) void mega_kernel(
    const float* __restrict__ x, const float* __restrict__ W,
    const float* __restrict__ b_enc, const float* __restrict__ W_dec,
    const float* __restrict__ b_dec,
    float* __restrict__ out,              // [0]=loss, +1 xhat, +1+393216 z
    float* __restrict__ A_T, float* __restrict__ partial,
    float* __restrict__ sel_val, int* __restrict__ sel_idx,
    unsigned* __restrict__ bar)
{
    __shared__ MegaSm sm;
    const int tid = threadIdx.x;
    const int bid = blockIdx.x;
    float* xhat = out + 1;
    float* z    = out + 1 + 393216;

    // ================= phase 0: prep (A_T[k][b]) =================
    {
        int gg = bid * 256 + tid;
        if (gg < 24576) {
            int b = gg / DIN, d = gg - b * DIN;
            const float* xp = x + (size_t)b * TD + d;
            float S = 0.f, x0 = xp[0], xl = xp[15 * DIN];
            #pragma unroll
            for (int t = 0; t < 16; ++t) S += xp[t * DIN];
            int base = d * 96 + b;
            A_T[base]      = S - xl;
            A_T[base + 32] = S;
            A_T[base + 64] = S - x0;
        }
        if (bid == NBLK - 1 && tid == 0) out[0] = 0.f;
    }
    grid_barrier(bar, bar + 1);

    // ================= phase 1: encode GEMM (R5 verbatim) =================
    {
        const int ks = bid & 7, s0 = (bid >> 3) * SB, koff = ks * KLEN;
        const int l = tid & 63, w = tid >> 6;

        float4 wreg[8];
        #pragma unroll
        for (int i = 0; i < 8; ++i) {
            int f4 = tid + (i << 8);
            int row = f4 >> 3, c = (f4 & 7) << 2;
            wreg[i] = *(const float4*)&W[(size_t)(s0 + row) * KTOT + koff + c];
        }
        {
            const float4* src = (const float4*)&A_T[koff * 32];
            #pragma unroll
            for (int j = 0; j < 9; ++j) {
                int f = tid + (j << 8);
                int k = f >> 3, q = f & 7;
                float4 v = src[f];
                *(float4*)&sm.e.A_lds[k * 32 + ((q << 2) ^ ((k & 7) << 2))] = v;
            }
        }
        float4 acc0[4], acc1[4];
        #pragma unroll
        for (int m = 0; m < 4; ++m) {
            acc0[m] = make_float4(0.f, 0.f, 0.f, 0.f);
            acc1[m] = make_float4(0.f, 0.f, 0.f, 0.f);
        }
        #pragma unroll 1
        for (int ch = 0; ch < NCH; ++ch) {
            __syncthreads();
            #pragma unroll
            for (int i = 0; i < 8; ++i) {
                int f4 = tid + (i << 8);
                int row = f4 >> 3, c = (f4 & 7) << 2;
                *(float4*)&sm.e.Wt[row * WSTR + c] = wreg[i];
            }
            __syncthreads();
            if (ch + 1 < NCH) {
                const int kc = (ch + 1) * KC;
                #pragma unroll
                for (int i = 0; i < 8; ++i) {
                    int f4 = tid + (i << 8);
                    int row = f4 >> 3, c = (f4 & 7) << 2;
                    wreg[i] = *(const float4*)&W[(size_t)(s0 + row) * KTOT + koff + kc + c];
                }
            }
            #pragma unroll
            for (int gq = 0; gq < 8; ++gq) {
                const int kk0 = gq << 2;
                float4 a0[4], a1[4];
                #pragma unroll
                for (int d = 0; d < 4; ++d) {
                    const int k = ch * KC + kk0 + d;
                    a0[d] = *(const float4*)&sm.e.A_lds[aidx(k, w << 3)];
                    a1[d] = *(const float4*)&sm.e.A_lds[aidx(k, (w << 3) + 4)];
                }
                #pragma unroll
                for (int m = 0; m < 4; ++m) {
                    float4 wv = *(const float4*)&sm.e.Wt[(l + (m << 6)) * WSTR + kk0];
                    FMA4(acc0[m], wv.x, a0[0]); FMA4(acc0[m], wv.y, a0[1]);
                    FMA4(acc0[m], wv.z, a0[2]); FMA4(acc0[m], wv.w, a0[3]);
                    FMA4(acc1[m], wv.x, a1[0]); FMA4(acc1[m], wv.y, a1[1]);
                    FMA4(acc1[m], wv.z, a1[2]); FMA4(acc1[m], wv.w, a1[3]);
                }
            }
        }
        float* pb = partial + (size_t)(ks * 32 + (w << 3)) * DSAE + s0 + l;
        #pragma unroll
        for (int m = 0; m < 4; ++m) {
            const int so = m << 6;
            pb[(size_t)0 * DSAE + so] = acc0[m].x;
            pb[(size_t)1 * DSAE + so] = acc0[m].y;
            pb[(size_t)2 * DSAE + so] = acc0[m].z;
            pb[(size_t)3 * DSAE + so] = acc0[m].w;
            pb[(size_t)4 * DSAE + so] = acc1[m].x;
            pb[(size_t)5 * DSAE + so] = acc1[m].y;
            pb[(size_t)6 * DSAE + so] = acc1[m].z;
            pb[(size_t)7 * DSAE + so] = acc1[m].w;
        }
    }
    grid_barrier(bar, bar + 1);

    // ================= phase 2: combine (1 float4 per thread) =================
    {
        int gg = bid * 256 + tid;                 // 0..131071
        int b = gg >> 12, s4 = gg & 4095;
        const float4* p = (const float4*)partial;
        float4 acc = p[(size_t)b * 4096 + s4];
        #pragma unroll
        for (int k2 = 1; k2 < KSPLIT; ++k2) {
            float4 v = p[(size_t)(k2 * 32 + b) * 4096 + s4];
            acc.x += v.x; acc.y += v.y; acc.z += v.z; acc.w += v.w;
        }
        float4 be = ((const float4*)b_enc)[s4];
        acc.x += be.x; acc.y += be.y; acc.z += be.z; acc.w += be.w;
        ((float4*)z)[(size_t)b * 4096 + s4] = acc;
    }
    grid_barrier(bar, bar + 1);

    // ================= phase 3: radix top-k (blocks 0..31) =================
    if (bid < 32) {
        float* zrow = z + (size_t)bid * DSAE;
        unsigned prefix = 0, pmask = 0;
        int need = K_;
        for (int p = 0; p < 4; ++p) {
            const int shift = 24 - 8 * p;
            sm.t.hist[tid] = 0;
            __syncthreads();
            #pragma unroll 8
            for (int i = 0; i < 64; ++i) {
                unsigned xb = __float_as_uint(zrow[tid + (i << 8)]);
                unsigned u = (xb & 0x80000000u) ? ~xb : (xb | 0x80000000u);
                if ((u & pmask) == prefix) atomicAdd(&sm.t.hist[(u >> shift) & 255u], 1u);
            }
            __syncthreads();
            if (tid < 64) {
                unsigned s4 = sm.t.hist[4*tid] + sm.t.hist[4*tid+1]
                            + sm.t.hist[4*tid+2] + sm.t.hist[4*tid+3];
                #pragma unroll
                for (int off = 1; off < 64; off <<= 1) {
                    unsigned o = __shfl_down(s4, off, 64);
                    if (tid + off < 64) s4 += o;
                }
                sm.t.gsfx[tid] = s4;
                if (tid == 0) sm.t.gsfx[64] = 0;
            }
            __syncthreads();
            {
                int q = tid >> 2;
                unsigned a = sm.t.gsfx[q + 1];
                for (int dd = 4*q + 3; dd >= tid; --dd) a += sm.t.hist[dd];
                sm.t.sfx[tid] = a;
                if (tid == 0) sm.t.sfx[256] = 0;
            }
            __syncthreads();
            if (sm.t.sfx[tid] >= (unsigned)need && sm.t.sfx[tid + 1] < (unsigned)need)
                sm.t.sdelta = tid;
            __syncthreads();
            const int dlt = sm.t.sdelta;
            need   -= (int)sm.t.sfx[dlt + 1];
            prefix |= ((unsigned)dlt) << shift;
            pmask  |= 0xFFu << shift;
            __syncthreads();
        }
        const unsigned ustar = prefix;
        if (tid == 0) sm.t.scnt = 0;
        __syncthreads();
        unsigned long long eqmask = 0;
        #pragma unroll 8
        for (int i = 0; i < 64; ++i) {
            int idx = tid + (i << 8);
            float f = zrow[idx];
            unsigned xb = __float_as_uint(f);
            unsigned u = (xb & 0x80000000u) ? ~xb : (xb | 0x80000000u);
            if (u > ustar) {
                unsigned s = atomicAdd(&sm.t.scnt, 1u);
                sm.t.l_idx[s] = idx; sm.t.l_val[s] = f;
            } else if (u == ustar) {
                eqmask |= (1ull << i);
            }
        }
        __syncthreads();
        const int needf = need;
        for (int r = 0; r < needf; ++r) {
            if (tid == 0) sm.t.eq_min = 0x7FFFFFFF;
            __syncthreads();
            #pragma unroll 8
            for (int i = 0; i < 64; ++i)
                if ((eqmask >> i) & 1ull) atomicMin(&sm.t.eq_min, tid + (i << 8));
            __syncthreads();
            #pragma unroll 8
            for (int i = 0; i < 64; ++i)
                if (((eqmask >> i) & 1ull) && (tid + (i << 8) == sm.t.eq_min)) {
                    eqmask &= ~(1ull << i);
                    unsigned s = atomicAdd(&sm.t.scnt, 1u);
                    sm.t.l_idx[s] = sm.t.eq_min; sm.t.l_val[s] = zrow[sm.t.eq_min];
                }
            __syncthreads();
        }
        __syncthreads();
        #pragma unroll 8
        for (int i = 0; i < 64; ++i) zrow[tid + (i << 8)] = 0.f;
        __syncthreads();
        if (tid == 0) {
            for (int a2 = 1; a2 < K_; ++a2) {
                int ia = sm.t.l_idx[a2]; float va = sm.t.l_val[a2]; int c = a2 - 1;
                while (c >= 0 && sm.t.l_idx[c] > ia) {
                    sm.t.l_idx[c+1] = sm.t.l_idx[c]; sm.t.l_val[c+1] = sm.t.l_val[c]; --c;
                }
                sm.t.l_idx[c+1] = ia; sm.t.l_val[c+1] = va;
            }
        }
        __syncthreads();
        if (tid < K_) {
            float val = sm.t.l_val[tid] > 0.f ? sm.t.l_val[tid] : 0.f;
            zrow[sm.t.l_idx[tid]] = val;
            sel_val[(bid << 5) + tid] = val;
            sel_idx[(bid << 5) + tid] = sm.t.l_idx[tid];
        }
    }
    grid_barrier(bar, bar + 1);

    // ================= phase 4: decode + loss =================
    if (bid < 384) {
        const int b = bid / 12, chunk = bid - b * 12;
        if (tid < K_) { sm.d.sv[tid] = sel_val[(b << 5) + tid];
                        sm.d.si[tid] = sel_idx[(b << 5) + tid]; }
        __syncthreads();
        const int e = chunk * 1024 + tid * 4;
        float4 acc = *(const float4*)&b_dec[e];
        #pragma unroll 8
        for (int j = 0; j < K_; ++j) {
            const float val = sm.d.sv[j];
            const float4 wd = *(const float4*)&W_dec[(size_t)sm.d.si[j] * TD + e];
            acc.x += val * wd.x; acc.y += val * wd.y;
            acc.z += val * wd.z; acc.w += val * wd.w;
        }
        const size_t xo = (size_t)b * TD + e;
        xhat[xo + 0] = acc.x; xhat[xo + 1] = acc.y;
        xhat[xo + 2] = acc.z; xhat[xo + 3] = acc.w;
        const float4 xv = *(const float4*)&x[xo];
        float dx = acc.x - xv.x, dy = acc.y - xv.y;
        float dz = acc.z - xv.z, dw = acc.w - xv.w;
        float ss = dx*dx + dy*dy + dz*dz + dw*dw;
        #pragma unroll
        for (int off = 32; off > 0; off >>= 1) ss += __shfl_down(ss, off, 64);
        if ((tid & 63) == 0) sm.d.wsum[tid >> 6] = ss;
        __syncthreads();
        if (tid == 0)
            atomicAdd(out, (sm.d.wsum[0] + sm.d.wsum[1] + sm.d.wsum[2] + sm.d.wsum[3])
                            * (1.0f / 512.0f));
    }
}

extern "C" void kernel_launch(void* const* d_in, const int* in_sizes, int n_in,
                              void* d_out, int out_size, void* d_ws, size_t ws_size,
                              hipStream_t stream) {
    const float* x      = (const float*)d_in[0];
    const float* conv_w = (const float*)d_in[1];
    const float* b_enc  = (const float*)d_in[2];
    const float* W_dec  = (const float*)d_in[3];
    const float* b_dec  = (const float*)d_in[4];

    float*    out         = (float*)d_out;
    float*    partial_enc = (float*)d_ws;                              // 16.8 MB
    float*    A_T         = (float*)((char*)d_ws + (20u << 20));       // 96 KB
    float*    sel_val     = (float*)((char*)d_ws + (21u << 20));
    int*      sel_idx     = (int*)  ((char*)d_ws + (21u << 20) + 4096);
    unsigned* bar         = (unsigned*)((char*)d_ws + (21u << 20) + 12288);

    hipMemsetAsync(bar, 0, 8, stream);           // {count, gen} must start at 0
    mega_kernel<<<NBLK, 256, 0, stream>>>(x, conv_w, b_enc, W_dec, b_dec,
                                          out, A_T, partial_enc,
                                          sel_val, sel_idx, bar);
}

// Round 8
// 182.793 us; speedup vs baseline: 5.2176x; 5.2176x over previous
//
#include <hip/hip_runtime.h>
#include <hip/hip_bf16.h>
#include <float.h>

#define DIN   768
#define DSAE  16384
#define K_    32
#define KTOT  2304
#define TD    12288   // 16*768
#define KSPLIT 8
#define KLEN   288    // KTOT/KSPLIT
#define KC     32
#define NCH    9      // KLEN/KC
#define SB     256    // s-rows per enc block (2 blocks/CU)
#define WSTR   36

#define FMA4(ACC, S, A) { ACC.x += (S) * (A).x; ACC.y += (S) * (A).y; \
                          ACC.z += (S) * (A).z; ACC.w += (S) * (A).w; }

__device__ __forceinline__ int aidx(int k, int b) {   // XOR-swizzled A_lds layout
    return k * 32 + (b ^ ((k & 7) << 2));
}

// ---------------- Kernel 1: prep — build A_T[k][b], k = d*3+j ----------------
__global__ __launch_bounds__(256) void prep_kernel(const float* __restrict__ x,
                                                   float* __restrict__ A_T) {
    int g = blockIdx.x * 256 + threadIdx.x;      // 0..24575
    int b = g / DIN;
    int d = g - b * DIN;
    const float* xp = x + (size_t)b * TD + d;
    float S = 0.f;
    float x0 = xp[0];
    float xl = xp[15 * DIN];
    #pragma unroll
    for (int t = 0; t < 16; ++t) S += xp[t * DIN];
    int base = d * 96 + b;                       // (d*3+j)*32 + b
    A_T[base]      = S - xl;                     // j=0
    A_T[base + 32] = S;                          // j=1
    A_T[base + 64] = S - x0;                     // j=2
}

// ---------------- Kernel 2: encode GEMM (256s x 32b tile, 2 blocks/CU) ----------------
// grid = 64 s-tiles x 8 k-splits = 512. wave w: b = 8w..8w+7; lane l: rows l+64m, m 0..3.
__global__ __launch_bounds__(256, 2) void enc_gemm_kernel(
    const float* __restrict__ W,      // conv_w (16384 x 2304)
    const float* __restrict__ A_T,    // (2304 x 32)
    float* __restrict__ partial)      // (8 x 32 x 16384)
{
    __shared__ float Wt[SB * WSTR];      // 36864 B
    __shared__ float A_lds[KLEN * 32];   // 36864 B (swizzled)

    const int tid  = threadIdx.x;
    const int ks   = blockIdx.x & 7;
    const int s0   = (blockIdx.x >> 3) * SB;
    const int koff = ks * KLEN;
    const int l    = tid & 63;
    const int w    = tid >> 6;

    // W chunk-0 prefetch (8 float4/thread)
    float4 wreg[8];
    #pragma unroll
    for (int i = 0; i < 8; ++i) {
        int f4 = tid + (i << 8);                 // 0..2047
        int row = f4 >> 3, c = (f4 & 7) << 2;
        wreg[i] = *(const float4*)&W[(size_t)(s0 + row) * KTOT + koff + c];
    }

    // stage ENTIRE A-slice once: 288k x 32b = 2304 float4, 9/thread
    {
        const float4* src = (const float4*)&A_T[koff * 32];
        #pragma unroll
        for (int j = 0; j < 9; ++j) {
            int f = tid + (j << 8);              // float4 index
            int k = f >> 3, q = f & 7;
            float4 v = src[f];
            *(float4*)&A_lds[k * 32 + ((q << 2) ^ ((k & 7) << 2))] = v;
        }
    }

    float4 acc0[4], acc1[4];
    #pragma unroll
    for (int m = 0; m < 4; ++m) {
        acc0[m] = make_float4(0.f, 0.f, 0.f, 0.f);
        acc1[m] = make_float4(0.f, 0.f, 0.f, 0.f);
    }

    #pragma unroll 1
    for (int ch = 0; ch < NCH; ++ch) {
        __syncthreads();                         // prev compute done (and A ready at ch0)
        #pragma unroll
        for (int i = 0; i < 8; ++i) {
            int f4 = tid + (i << 8);
            int row = f4 >> 3, c = (f4 & 7) << 2;
            *(float4*)&Wt[row * WSTR + c] = wreg[i];
        }
        __syncthreads();

        if (ch + 1 < NCH) {                      // prefetch next W chunk under compute
            const int kc = (ch + 1) * KC;
            #pragma unroll
            for (int i = 0; i < 8; ++i) {
                int f4 = tid + (i << 8);
                int row = f4 >> 3, c = (f4 & 7) << 2;
                wreg[i] = *(const float4*)&W[(size_t)(s0 + row) * KTOT + koff + kc + c];
            }
        }

        #pragma unroll
        for (int g = 0; g < 8; ++g) {
            const int kk0 = g << 2;
            float4 a0[4], a1[4];
            #pragma unroll
            for (int d = 0; d < 4; ++d) {
                const int k = ch * KC + kk0 + d;
                a0[d] = *(const float4*)&A_lds[aidx(k, w << 3)];        // broadcast
                a1[d] = *(const float4*)&A_lds[aidx(k, (w << 3) + 4)];
            }
            #pragma unroll
            for (int m = 0; m < 4; ++m) {
                float4 wv = *(const float4*)&Wt[(l + (m << 6)) * WSTR + kk0];
                FMA4(acc0[m], wv.x, a0[0]); FMA4(acc0[m], wv.y, a0[1]);
                FMA4(acc0[m], wv.z, a0[2]); FMA4(acc0[m], wv.w, a0[3]);
                FMA4(acc1[m], wv.x, a1[0]); FMA4(acc1[m], wv.y, a1[1]);
                FMA4(acc1[m], wv.z, a1[2]); FMA4(acc1[m], wv.w, a1[3]);
            }
        }
    }

    // partial[ks][b][s], coalesced over l
    float* pb = partial + (size_t)(ks * 32 + (w << 3)) * DSAE + s0 + l;
    #pragma unroll
    for (int m = 0; m < 4; ++m) {
        const int so = m << 6;
        pb[(size_t)0 * DSAE + so] = acc0[m].x;
        pb[(size_t)1 * DSAE + so] = acc0[m].y;
        pb[(size_t)2 * DSAE + so] = acc0[m].z;
        pb[(size_t)3 * DSAE + so] = acc0[m].w;
        pb[(size_t)4 * DSAE + so] = acc1[m].x;
        pb[(size_t)5 * DSAE + so] = acc1[m].y;
        pb[(size_t)6 * DSAE + so] = acc1[m].z;
        pb[(size_t)7 * DSAE + so] = acc1[m].w;
    }
}

// ---------------- Kernel 3: combine K-split partials + bias (streaming) ----------------
__global__ __launch_bounds__(256) void combine_kernel(const float* __restrict__ partial,
                                                      const float* __restrict__ b_enc,
                                                      float* __restrict__ pre,
                                                      float* __restrict__ out0) {
    int g  = blockIdx.x * 256 + threadIdx.x;     // float4 index, 0..131071
    int b  = g >> 12;
    int s4 = g & 4095;
    const float4* p = (const float4*)partial;
    float4 acc = p[(size_t)b * 4096 + s4];
    #pragma unroll
    for (int ks = 1; ks < KSPLIT; ++ks) {
        float4 v = p[(size_t)(ks * 32 + b) * 4096 + s4];
        acc.x += v.x; acc.y += v.y; acc.z += v.z; acc.w += v.w;
    }
    float4 be = ((const float4*)b_enc)[s4];
    acc.x += be.x; acc.y += be.y; acc.z += be.z; acc.w += be.w;
    ((float4*)pre)[(size_t)b * 4096 + s4] = acc;
    if (g == 0) *out0 = 0.f;
}

// ---------------- Kernel 4: top-k via 4-pass radix select (exact lax.top_k) ----------------
__global__ __launch_bounds__(1024, 1) void topk_kernel(
    float* __restrict__ z,            // in: pre (32 x DSAE); out: sparse z
    float* __restrict__ sel_val,
    int*   __restrict__ sel_idx)
{
    __shared__ unsigned hist[256];
    __shared__ unsigned gsfx[65];
    __shared__ unsigned sfx[257];
    __shared__ int      sdelta;
    __shared__ unsigned scnt;
    __shared__ int      l_idx[K_];
    __shared__ float    l_val[K_];
    __shared__ int      eq_min;

    const int t = threadIdx.x;
    const int b = blockIdx.x;
    float* zrow = z + (size_t)b * DSAE;

    float v[16]; unsigned u[16];
    #pragma unroll
    for (int i = 0; i < 16; ++i) {
        float f = zrow[t + (i << 10)];
        v[i] = f;
        unsigned xb = __float_as_uint(f);
        u[i] = (xb & 0x80000000u) ? ~xb : (xb | 0x80000000u);
    }

    unsigned prefix = 0, pmask = 0;
    int need = K_;

    for (int p = 0; p < 4; ++p) {
        const int shift = 24 - 8 * p;
        if (t < 256) hist[t] = 0;
        __syncthreads();
        #pragma unroll
        for (int i = 0; i < 16; ++i)
            if ((u[i] & pmask) == prefix)
                atomicAdd(&hist[(u[i] >> shift) & 255u], 1u);
        __syncthreads();
        if (t < 64) {
            unsigned s4 = hist[4*t] + hist[4*t+1] + hist[4*t+2] + hist[4*t+3];
            #pragma unroll
            for (int off = 1; off < 64; off <<= 1) {
                unsigned o = __shfl_down(s4, off, 64);
                if (t + off < 64) s4 += o;
            }
            gsfx[t] = s4;
            if (t == 0) gsfx[64] = 0;
        }
        __syncthreads();
        if (t < 256) {
            int q = t >> 2;
            unsigned acc = gsfx[q + 1];
            for (int d = 4*q + 3; d >= t; --d) acc += hist[d];
            sfx[t] = acc;
            if (t == 0) sfx[256] = 0;
        }
        __syncthreads();
        if (t < 256) {
            if (sfx[t] >= (unsigned)need && sfx[t + 1] < (unsigned)need) sdelta = t;
        }
        __syncthreads();
        const int dlt = sdelta;
        need  -= (int)sfx[dlt + 1];
        prefix |= ((unsigned)dlt) << shift;
        pmask  |= 0xFFu << shift;
        __syncthreads();
    }

    const unsigned ustar = prefix;
    if (t == 0) scnt = 0;
    __syncthreads();

    unsigned eqmask = 0;
    #pragma unroll
    for (int i = 0; i < 16; ++i) {
        int idx = t + (i << 10);
        if (u[i] > ustar) {
            unsigned s = atomicAdd(&scnt, 1u);
            l_idx[s] = idx; l_val[s] = v[i];
        } else if (u[i] == ustar) {
            eqmask |= (1u << i);
        }
    }
    __syncthreads();
    const int needf = need;
    for (int r = 0; r < needf; ++r) {
        if (t == 0) eq_min = 0x7FFFFFFF;
        __syncthreads();
        #pragma unroll
        for (int i = 0; i < 16; ++i)
            if (eqmask & (1u << i)) atomicMin(&eq_min, t + (i << 10));
        __syncthreads();
        #pragma unroll
        for (int i = 0; i < 16; ++i)
            if ((eqmask & (1u << i)) && (t + (i << 10) == eq_min)) {
                eqmask &= ~(1u << i);
                unsigned s = atomicAdd(&scnt, 1u);
                l_idx[s] = eq_min; l_val[s] = v[i];
            }
        __syncthreads();
    }

    #pragma unroll
    for (int i = 0; i < 16; ++i) zrow[t + (i << 10)] = 0.f;
    __syncthreads();
    if (t == 0) {
        for (int a = 1; a < K_; ++a) {
            int ia = l_idx[a]; float va = l_val[a]; int c = a - 1;
            while (c >= 0 && l_idx[c] > ia) {
                l_idx[c+1] = l_idx[c]; l_val[c+1] = l_val[c]; --c;
            }
            l_idx[c+1] = ia; l_val[c+1] = va;
        }
    }
    __syncthreads();
    if (t < K_) {
        float val = l_val[t] > 0.f ? l_val[t] : 0.f;
        zrow[l_idx[t]] = val;
        sel_val[(b << 5) + t] = val;
        sel_idx[(b << 5) + t] = l_idx[t];
    }
}

// ---------------- Kernel 5: sparse decode + fused sq-err, atomic loss ----------------
__global__ __launch_bounds__(256, 4) void decode_kernel(
    const float* __restrict__ W_dec,
    const float* __restrict__ b_dec,
    const float* __restrict__ x,
    const float* __restrict__ sel_val,
    const int*   __restrict__ sel_idx,
    float* __restrict__ xhat,          // d_out + 1
    float* __restrict__ out0)
{
    __shared__ float sv[K_];
    __shared__ int   si[K_];
    __shared__ float wsum[4];

    const int t     = threadIdx.x;
    const int blk   = blockIdx.x;
    const int b     = blk / 12;
    const int chunk = blk - b * 12;

    if (t < K_) { sv[t] = sel_val[(b << 5) + t]; si[t] = sel_idx[(b << 5) + t]; }
    __syncthreads();

    const int e = chunk * 1024 + t * 4;
    float4 acc = *(const float4*)&b_dec[e];
    #pragma unroll 8
    for (int j = 0; j < K_; ++j) {
        const float val = sv[j];
        const float4 wd = *(const float4*)&W_dec[(size_t)si[j] * TD + e];
        acc.x += val * wd.x;
        acc.y += val * wd.y;
        acc.z += val * wd.z;
        acc.w += val * wd.w;
    }

    const size_t xo = (size_t)b * TD + e;
    xhat[xo + 0] = acc.x;
    xhat[xo + 1] = acc.y;
    xhat[xo + 2] = acc.z;
    xhat[xo + 3] = acc.w;

    const float4 xv = *(const float4*)&x[xo];
    float dx = acc.x - xv.x, dy = acc.y - xv.y;
    float dz = acc.z - xv.z, dw = acc.w - xv.w;
    float ss = dx * dx + dy * dy + dz * dz + dw * dw;
    #pragma unroll
    for (int off = 32; off > 0; off >>= 1) ss += __shfl_down(ss, off, 64);
    if ((t & 63) == 0) wsum[t >> 6] = ss;
    __syncthreads();
    if (t == 0)
        atomicAdd(out0, (wsum[0] + wsum[1] + wsum[2] + wsum[3]) * (1.0f / 512.0f));
}

extern "C" void kernel_launch(void* const* d_in, const int* in_sizes, int n_in,
                              void* d_out, int out_size, void* d_ws, size_t ws_size,
                              hipStream_t stream) {
    const float* x      = (const float*)d_in[0];
    const float* conv_w = (const float*)d_in[1];
    const float* b_enc  = (const float*)d_in[2];
    const float* W_dec  = (const float*)d_in[3];
    const float* b_dec  = (const float*)d_in[4];

    float* out  = (float*)d_out;
    float* xhat = out + 1;                        // (32,16,768)
    float* z    = out + 1 + 393216;               // (32,16384) — holds pre then sparse z

    float* partial_enc = (float*)d_ws;                          // 16.8 MB
    float* A_T         = (float*)((char*)d_ws + (20u << 20));   // 288 KB
    float* sel_val     = (float*)((char*)d_ws + (21u << 20));
    int*   sel_idx     = (int*)  ((char*)d_ws + (21u << 20) + 4096);

    prep_kernel    <<<96,  256,  0, stream>>>(x, A_T);
    // PROBE: enc launched twice (idempotent pure-write kernel).
    // dur_us - 123.9 = true enc time; everything else identical to R5.
    enc_gemm_kernel<<<512, 256,  0, stream>>>(conv_w, A_T, partial_enc);
    enc_gemm_kernel<<<512, 256,  0, stream>>>(conv_w, A_T, partial_enc);
    combine_kernel <<<512, 256,  0, stream>>>(partial_enc, b_enc, z, out);
    topk_kernel    <<<32,  1024, 0, stream>>>(z, sel_val, sel_idx);
    decode_kernel  <<<384, 256,  0, stream>>>(W_dec, b_dec, x, sel_val, sel_idx, xhat, out);
}

// Round 9
// 154.690 us; speedup vs baseline: 6.1654x; 1.1817x over previous
//
#include <hip/hip_runtime.h>
#include <hip/hip_bf16.h>
#include <float.h>

#define DIN   768
#define DSAE  16384
#define K_    32
#define KTOT  2304
#define TD    12288   // 16*768
#define KSPLIT 16
#define KLEN   144    // KTOT/KSPLIT
#define KC     24     // k per staged chunk
#define NCH    6      // KLEN/KC
#define SB     256    // s-rows per enc block
#define WSTR   28     // Wt stride: 16B-aligned rows, uniform bank spread

#define FMA4(ACC, S, A) { ACC.x += (S) * (A).x; ACC.y += (S) * (A).y; \
                          ACC.z += (S) * (A).z; ACC.w += (S) * (A).w; }

// ---------------- Kernel 1: prep — build A_T[k][b], k = d*3+j ----------------
__global__ __launch_bounds__(256) void prep_kernel(const float* __restrict__ x,
                                                   float* __restrict__ A_T) {
    int g = blockIdx.x * 256 + threadIdx.x;      // 0..24575
    int b = g / DIN;
    int d = g - b * DIN;
    const float* xp = x + (size_t)b * TD + d;
    float S = 0.f;
    float x0 = xp[0];
    float xl = xp[15 * DIN];
    #pragma unroll
    for (int t = 0; t < 16; ++t) S += xp[t * DIN];
    int base = d * 96 + b;                       // (d*3+j)*32 + b
    A_T[base]      = S - xl;                     // j=0
    A_T[base + 32] = S;                          // j=1
    A_T[base + 64] = S - x0;                     // j=2
}

// ------------- Kernel 2: encode GEMM (256s x 32b tile, 4 blocks/CU) -------------
// grid = 64 s-tiles x 16 k-splits = 1024. wave w: b = 8w..8w+7; lane l: s-rows l+64m.
__global__ __launch_bounds__(256, 4) void enc_gemm_kernel(
    const float* __restrict__ W,      // conv_w (16384 x 2304)
    const float* __restrict__ A_T,    // (2304 x 32)
    float* __restrict__ partial)      // (16 x 32 x 16384)
{
    __shared__ float Wt[SB * WSTR];   // 28672 B
    __shared__ float Ac[KC * 32];     // 3072 B, [kk][b] linear (broadcast reads)

    const int tid  = threadIdx.x;
    const int ks   = blockIdx.x & 15;
    const int s0   = (blockIdx.x >> 4) * SB;
    const int koff = ks * KLEN;
    const int l    = tid & 63;
    const int w    = tid >> 6;

    // chunk-0 prefetch into registers (W: 6 float4/thread; A: 1 float4 for tid<192)
    float4 wreg[6];
    float4 areg = make_float4(0.f, 0.f, 0.f, 0.f);
    #pragma unroll
    for (int i = 0; i < 6; ++i) {
        int f4  = tid + (i << 8);                // 0..1535
        int row = f4 / 6, c4 = (f4 - row * 6) << 2;
        wreg[i] = *(const float4*)&W[(size_t)(s0 + row) * KTOT + koff + c4];
    }
    if (tid < 192) areg = ((const float4*)(A_T + koff * 32))[tid];

    float4 acc0[4], acc1[4];
    #pragma unroll
    for (int m = 0; m < 4; ++m) {
        acc0[m] = make_float4(0.f, 0.f, 0.f, 0.f);
        acc1[m] = make_float4(0.f, 0.f, 0.f, 0.f);
    }

    #pragma unroll 1
    for (int ch = 0; ch < NCH; ++ch) {
        __syncthreads();                         // prev compute done
        #pragma unroll
        for (int i = 0; i < 6; ++i) {
            int f4  = tid + (i << 8);
            int row = f4 / 6, c4 = (f4 - row * 6) << 2;
            *(float4*)&Wt[row * WSTR + c4] = wreg[i];
        }
        if (tid < 192) *(float4*)&Ac[tid << 2] = areg;
        __syncthreads();

        if (ch + 1 < NCH) {                      // prefetch next chunk under compute
            const int kc = (ch + 1) * KC;
            #pragma unroll
            for (int i = 0; i < 6; ++i) {
                int f4  = tid + (i << 8);
                int row = f4 / 6, c4 = (f4 - row * 6) << 2;
                wreg[i] = *(const float4*)&W[(size_t)(s0 + row) * KTOT + koff + kc + c4];
            }
            if (tid < 192) areg = ((const float4*)(A_T + (koff + kc) * 32))[tid];
        }

        #pragma unroll
        for (int g = 0; g < 6; ++g) {
            const int kk0 = g << 2;
            float4 wv0 = *(const float4*)&Wt[(l      ) * WSTR + kk0];
            float4 wv1 = *(const float4*)&Wt[(l +  64) * WSTR + kk0];
            float4 wv2 = *(const float4*)&Wt[(l + 128) * WSTR + kk0];
            float4 wv3 = *(const float4*)&Wt[(l + 192) * WSTR + kk0];
            #pragma unroll
            for (int d = 0; d < 4; ++d) {
                float4 a0 = *(const float4*)&Ac[(kk0 + d) * 32 + (w << 3)];     // broadcast
                float4 a1 = *(const float4*)&Ac[(kk0 + d) * 32 + (w << 3) + 4]; // broadcast
                const float w0 = (&wv0.x)[d], w1 = (&wv1.x)[d];
                const float w2 = (&wv2.x)[d], w3 = (&wv3.x)[d];
                FMA4(acc0[0], w0, a0); FMA4(acc1[0], w0, a1);
                FMA4(acc0[1], w1, a0); FMA4(acc1[1], w1, a1);
                FMA4(acc0[2], w2, a0); FMA4(acc1[2], w2, a1);
                FMA4(acc0[3], w3, a0); FMA4(acc1[3], w3, a1);
            }
        }
    }

    // partial[ks][b][s], coalesced over l
    float* pb = partial + (size_t)(ks * 32 + (w << 3)) * DSAE + s0 + l;
    #pragma unroll
    for (int m = 0; m < 4; ++m) {
        const int so = m << 6;
        pb[(size_t)0 * DSAE + so] = acc0[m].x;
        pb[(size_t)1 * DSAE + so] = acc0[m].y;
        pb[(size_t)2 * DSAE + so] = acc0[m].z;
        pb[(size_t)3 * DSAE + so] = acc0[m].w;
        pb[(size_t)4 * DSAE + so] = acc1[m].x;
        pb[(size_t)5 * DSAE + so] = acc1[m].y;
        pb[(size_t)6 * DSAE + so] = acc1[m].z;
        pb[(size_t)7 * DSAE + so] = acc1[m].w;
    }
}

// ---------------- Kernel 3: combine K-split partials + bias (streaming) ----------------
__global__ __launch_bounds__(256) void combine_kernel(const float* __restrict__ partial,
                                                      const float* __restrict__ b_enc,
                                                      float* __restrict__ pre,
                                                      float* __restrict__ out0) {
    int g  = blockIdx.x * 256 + threadIdx.x;     // float4 index, 0..131071
    int b  = g >> 12;
    int s4 = g & 4095;
    const float4* p = (const float4*)partial;
    float4 acc = p[(size_t)b * 4096 + s4];
    #pragma unroll
    for (int ks = 1; ks < KSPLIT; ++ks) {
        float4 v = p[(size_t)(ks * 32 + b) * 4096 + s4];
        acc.x += v.x; acc.y += v.y; acc.z += v.z; acc.w += v.w;
    }
    float4 be = ((const float4*)b_enc)[s4];
    acc.x += be.x; acc.y += be.y; acc.z += be.z; acc.w += be.w;
    ((float4*)pre)[(size_t)b * 4096 + s4] = acc;
    if (g == 0) *out0 = 0.f;
}

// ---------------- Kernel 4: top-k via 4-pass radix select (exact lax.top_k) ----------------
__global__ __launch_bounds__(1024, 1) void topk_kernel(
    float* __restrict__ z,            // in: pre (32 x DSAE); out: sparse z
    float* __restrict__ sel_val,
    int*   __restrict__ sel_idx)
{
    __shared__ unsigned hist[256];
    __shared__ unsigned gsfx[65];
    __shared__ unsigned sfx[257];
    __shared__ int      sdelta;
    __shared__ unsigned scnt;
    __shared__ int      l_idx[K_];
    __shared__ float    l_val[K_];
    __shared__ int      eq_min;

    const int t = threadIdx.x;
    const int b = blockIdx.x;
    float* zrow = z + (size_t)b * DSAE;

    float v[16]; unsigned u[16];
    #pragma unroll
    for (int i = 0; i < 16; ++i) {
        float f = zrow[t + (i << 10)];
        v[i] = f;
        unsigned xb = __float_as_uint(f);
        u[i] = (xb & 0x80000000u) ? ~xb : (xb | 0x80000000u);
    }

    unsigned prefix = 0, pmask = 0;
    int need = K_;

    for (int p = 0; p < 4; ++p) {
        const int shift = 24 - 8 * p;
        if (t < 256) hist[t] = 0;
        __syncthreads();
        #pragma unroll
        for (int i = 0; i < 16; ++i)
            if ((u[i] & pmask) == prefix)
                atomicAdd(&hist[(u[i] >> shift) & 255u], 1u);
        __syncthreads();
        if (t < 64) {
            unsigned s4 = hist[4*t] + hist[4*t+1] + hist[4*t+2] + hist[4*t+3];
            #pragma unroll
            for (int off = 1; off < 64; off <<= 1) {
                unsigned o = __shfl_down(s4, off, 64);
                if (t + off < 64) s4 += o;
            }
            gsfx[t] = s4;
            if (t == 0) gsfx[64] = 0;
        }
        __syncthreads();
        if (t < 256) {
            int q = t >> 2;
            unsigned acc = gsfx[q + 1];
            for (int d = 4*q + 3; d >= t; --d) acc += hist[d];
            sfx[t] = acc;
            if (t == 0) sfx[256] = 0;
        }
        __syncthreads();
        if (t < 256) {
            if (sfx[t] >= (unsigned)need && sfx[t + 1] < (unsigned)need) sdelta = t;
        }
        __syncthreads();
        const int dlt = sdelta;
        need  -= (int)sfx[dlt + 1];
        prefix |= ((unsigned)dlt) << shift;
        pmask  |= 0xFFu << shift;
        __syncthreads();
    }

    const unsigned ustar = prefix;
    if (t == 0) scnt = 0;
    __syncthreads();

    unsigned eqmask = 0;
    #pragma unroll
    for (int i = 0; i < 16; ++i) {
        int idx = t + (i << 10);
        if (u[i] > ustar) {
            unsigned s = atomicAdd(&scnt, 1u);
            l_idx[s] = idx; l_val[s] = v[i];
        } else if (u[i] == ustar) {
            eqmask |= (1u << i);
        }
    }
    __syncthreads();
    const int needf = need;
    for (int r = 0; r < needf; ++r) {
        if (t == 0) eq_min = 0x7FFFFFFF;
        __syncthreads();
        #pragma unroll
        for (int i = 0; i < 16; ++i)
            if (eqmask & (1u << i)) atomicMin(&eq_min, t + (i << 10));
        __syncthreads();
        #pragma unroll
        for (int i = 0; i < 16; ++i)
            if ((eqmask & (1u << i)) && (t + (i << 10) == eq_min)) {
                eqmask &= ~(1u << i);
                unsigned s = atomicAdd(&scnt, 1u);
                l_idx[s] = eq_min; l_val[s] = v[i];
            }
        __syncthreads();
    }

    #pragma unroll
    for (int i = 0; i < 16; ++i) zrow[t + (i << 10)] = 0.f;
    __syncthreads();
    if (t == 0) {
        for (int a = 1; a < K_; ++a) {
            int ia = l_idx[a]; float va = l_val[a]; int c = a - 1;
            while (c >= 0 && l_idx[c] > ia) {
                l_idx[c+1] = l_idx[c]; l_val[c+1] = l_val[c]; --c;
            }
            l_idx[c+1] = ia; l_val[c+1] = va;
        }
    }
    __syncthreads();
    if (t < K_) {
        float val = l_val[t] > 0.f ? l_val[t] : 0.f;
        zrow[l_idx[t]] = val;
        sel_val[(b << 5) + t] = val;
        sel_idx[(b << 5) + t] = l_idx[t];
    }
}

// ---------------- Kernel 5: sparse decode + fused sq-err, atomic loss ----------------
__global__ __launch_bounds__(256, 4) void decode_kernel(
    const float* __restrict__ W_dec,
    const float* __restrict__ b_dec,
    const float* __restrict__ x,
    const float* __restrict__ sel_val,
    const int*   __restrict__ sel_idx,
    float* __restrict__ xhat,          // d_out + 1
    float* __restrict__ out0)
{
    __shared__ float sv[K_];
    __shared__ int   si[K_];
    __shared__ float wsum[4];

    const int t     = threadIdx.x;
    const int blk   = blockIdx.x;
    const int b     = blk / 12;
    const int chunk = blk - b * 12;

    if (t < K_) { sv[t] = sel_val[(b << 5) + t]; si[t] = sel_idx[(b << 5) + t]; }
    __syncthreads();

    const int e = chunk * 1024 + t * 4;
    float4 acc = *(const float4*)&b_dec[e];
    #pragma unroll 8
    for (int j = 0; j < K_; ++j) {
        const float val = sv[j];
        const float4 wd = *(const float4*)&W_dec[(size_t)si[j] * TD + e];
        acc.x += val * wd.x;
        acc.y += val * wd.y;
        acc.z += val * wd.z;
        acc.w += val * wd.w;
    }

    const size_t xo = (size_t)b * TD + e;
    xhat[xo + 0] = acc.x;
    xhat[xo + 1] = acc.y;
    xhat[xo + 2] = acc.z;
    xhat[xo + 3] = acc.w;

    const float4 xv = *(const float4*)&x[xo];
    float dx = acc.x - xv.x, dy = acc.y - xv.y;
    float dz = acc.z - xv.z, dw = acc.w - xv.w;
    float ss = dx * dx + dy * dy + dz * dz + dw * dw;
    #pragma unroll
    for (int off = 32; off > 0; off >>= 1) ss += __shfl_down(ss, off, 64);
    if ((t & 63) == 0) wsum[t >> 6] = ss;
    __syncthreads();
    if (t == 0)
        atomicAdd(out0, (wsum[0] + wsum[1] + wsum[2] + wsum[3]) * (1.0f / 512.0f));
}

extern "C" void kernel_launch(void* const* d_in, const int* in_sizes, int n_in,
                              void* d_out, int out_size, void* d_ws, size_t ws_size,
                              hipStream_t stream) {
    const float* x      = (const float*)d_in[0];
    const float* conv_w = (const float*)d_in[1];
    const float* b_enc  = (const float*)d_in[2];
    const float* W_dec  = (const float*)d_in[3];
    const float* b_dec  = (const float*)d_in[4];

    float* out  = (float*)d_out;
    float* xhat = out + 1;                        // (32,16,768)
    float* z    = out + 1 + 393216;               // (32,16384) — holds pre then sparse z

    float* partial_enc = (float*)d_ws;                          // 33.6 MB
    float* A_T         = (float*)((char*)d_ws + (40u << 20));   // 288 KB
    float* sel_val     = (float*)((char*)d_ws + (41u << 20));
    int*   sel_idx     = (int*)  ((char*)d_ws + (41u << 20) + 4096);

    prep_kernel    <<<96,   256,  0, stream>>>(x, A_T);
    enc_gemm_kernel<<<1024, 256,  0, stream>>>(conv_w, A_T, partial_enc);
    combine_kernel <<<512,  256,  0, stream>>>(partial_enc, b_enc, z, out);
    topk_kernel    <<<32,   1024, 0, stream>>>(z, sel_val, sel_idx);
    decode_kernel  <<<384,  256,  0, stream>>>(W_dec, b_dec, x, sel_val, sel_idx, xhat, out);
}

// Round 10
// 127.113 us; speedup vs baseline: 7.5030x; 1.2169x over previous
//
#include <hip/hip_runtime.h>
#include <hip/hip_bf16.h>
#include <float.h>

#define DIN   768
#define DSAE  16384
#define K_    32
#define KTOT  2304
#define TD    12288   // 16*768
#define KSPLIT 8
#define KLEN   288    // KTOT/KSPLIT
#define KC     32     // 128B-aligned k-chunks (R9 lesson: keep alignment)
#define NCH    9      // KLEN/KC
#define SB     256    // s-rows per enc block
#define WSTR   36

#define FMA4(ACC, S, A) { ACC.x += (S) * (A).x; ACC.y += (S) * (A).y; \
                          ACC.z += (S) * (A).z; ACC.w += (S) * (A).w; }

// ---------------- Kernel 1: prep — build A_T[k][b], k = d*3+j ----------------
__global__ __launch_bounds__(256) void prep_kernel(const float* __restrict__ x,
                                                   float* __restrict__ A_T) {
    int g = blockIdx.x * 256 + threadIdx.x;      // 0..24575
    int b = g / DIN;
    int d = g - b * DIN;
    const float* xp = x + (size_t)b * TD + d;
    float S = 0.f;
    float x0 = xp[0];
    float xl = xp[15 * DIN];
    #pragma unroll
    for (int t = 0; t < 16; ++t) S += xp[t * DIN];
    int base = d * 96 + b;                       // (d*3+j)*32 + b
    A_T[base]      = S - xl;                     // j=0
    A_T[base + 32] = S;                          // j=1
    A_T[base + 64] = S - x0;                     // j=2
}

// ------------- Kernel 2: encode GEMM, scalar-A variant (R5 structure) -------------
// grid = 64 s-tiles x 8 k-splits = 512 (2 blocks/CU). wave w: b = 8w..8w+7;
// lane l: s-rows l+64m, m 0..3. W staged in LDS (coalesced->strided);
// A read via wave-uniform SCALAR loads (s_load) -> zero LDS traffic for A.
__global__ __launch_bounds__(256, 2) void enc_gemm_kernel(
    const float* __restrict__ W,      // conv_w (16384 x 2304)
    const float* __restrict__ A_T,    // (2304 x 32)
    float* __restrict__ partial)      // (8 x 32 x 16384)
{
    __shared__ float Wt[SB * WSTR];   // 36864 B (only LDS user now)

    const int tid  = threadIdx.x;
    const int ks   = blockIdx.x & 7;
    const int s0   = (blockIdx.x >> 3) * SB;
    const int koff = ks * KLEN;
    const int l    = tid & 63;
    const int w    = tid >> 6;

    // wave-uniform A base pointer -> scalar loads
    const float* Au = A_T + koff * 32 + __builtin_amdgcn_readfirstlane(w << 3);

    // W chunk-0 prefetch (8 float4/thread, 128B-aligned rows)
    float4 wreg[8];
    #pragma unroll
    for (int i = 0; i < 8; ++i) {
        int f4 = tid + (i << 8);                 // 0..2047
        int row = f4 >> 3, c = (f4 & 7) << 2;
        wreg[i] = *(const float4*)&W[(size_t)(s0 + row) * KTOT + koff + c];
    }

    float4 acc0[4], acc1[4];
    #pragma unroll
    for (int m = 0; m < 4; ++m) {
        acc0[m] = make_float4(0.f, 0.f, 0.f, 0.f);
        acc1[m] = make_float4(0.f, 0.f, 0.f, 0.f);
    }

    #pragma unroll 1
    for (int ch = 0; ch < NCH; ++ch) {
        __syncthreads();                         // prev compute done
        #pragma unroll
        for (int i = 0; i < 8; ++i) {
            int f4 = tid + (i << 8);
            int row = f4 >> 3, c = (f4 & 7) << 2;
            *(float4*)&Wt[row * WSTR + c] = wreg[i];
        }
        __syncthreads();

        if (ch + 1 < NCH) {                      // prefetch next W chunk under compute
            const int kc = (ch + 1) * KC;
            #pragma unroll
            for (int i = 0; i < 8; ++i) {
                int f4 = tid + (i << 8);
                int row = f4 >> 3, c = (f4 & 7) << 2;
                wreg[i] = *(const float4*)&W[(size_t)(s0 + row) * KTOT + koff + kc + c];
            }
        }

        #pragma unroll
        for (int g = 0; g < 8; ++g) {
            const int kk0 = g << 2;
            // A operand: 8 scalar float4 loads (wave-uniform -> s_load_dwordx4)
            float4 a0[4], a1[4];
            #pragma unroll
            for (int d = 0; d < 4; ++d) {
                const int k = ch * KC + kk0 + d;
                a0[d] = *(const float4*)&Au[k * 32];
                a1[d] = *(const float4*)&Au[k * 32 + 4];
            }
            #pragma unroll
            for (int m = 0; m < 4; ++m) {
                float4 wv = *(const float4*)&Wt[(l + (m << 6)) * WSTR + kk0];
                FMA4(acc0[m], wv.x, a0[0]); FMA4(acc0[m], wv.y, a0[1]);
                FMA4(acc0[m], wv.z, a0[2]); FMA4(acc0[m], wv.w, a0[3]);
                FMA4(acc1[m], wv.x, a1[0]); FMA4(acc1[m], wv.y, a1[1]);
                FMA4(acc1[m], wv.z, a1[2]); FMA4(acc1[m], wv.w, a1[3]);
            }
        }
    }

    // partial[ks][b][s], coalesced over l
    float* pb = partial + (size_t)(ks * 32 + (w << 3)) * DSAE + s0 + l;
    #pragma unroll
    for (int m = 0; m < 4; ++m) {
        const int so = m << 6;
        pb[(size_t)0 * DSAE + so] = acc0[m].x;
        pb[(size_t)1 * DSAE + so] = acc0[m].y;
        pb[(size_t)2 * DSAE + so] = acc0[m].z;
        pb[(size_t)3 * DSAE + so] = acc0[m].w;
        pb[(size_t)4 * DSAE + so] = acc1[m].x;
        pb[(size_t)5 * DSAE + so] = acc1[m].y;
        pb[(size_t)6 * DSAE + so] = acc1[m].z;
        pb[(size_t)7 * DSAE + so] = acc1[m].w;
    }
}

// ---------------- Kernel 3: combine K-split partials + bias (streaming) ----------------
__global__ __launch_bounds__(256) void combine_kernel(const float* __restrict__ partial,
                                                      const float* __restrict__ b_enc,
                                                      float* __restrict__ pre,
                                                      float* __restrict__ out0) {
    int g  = blockIdx.x * 256 + threadIdx.x;     // float4 index, 0..131071
    int b  = g >> 12;
    int s4 = g & 4095;
    const float4* p = (const float4*)partial;
    float4 acc = p[(size_t)b * 4096 + s4];
    #pragma unroll
    for (int ks = 1; ks < KSPLIT; ++ks) {
        float4 v = p[(size_t)(ks * 32 + b) * 4096 + s4];
        acc.x += v.x; acc.y += v.y; acc.z += v.z; acc.w += v.w;
    }
    float4 be = ((const float4*)b_enc)[s4];
    acc.x += be.x; acc.y += be.y; acc.z += be.z; acc.w += be.w;
    ((float4*)pre)[(size_t)b * 4096 + s4] = acc;
    if (g == 0) *out0 = 0.f;
}

// ---------------- Kernel 4: top-k via 4-pass radix select (exact lax.top_k) ----------------
__global__ __launch_bounds__(1024, 1) void topk_kernel(
    float* __restrict__ z,            // in: pre (32 x DSAE); out: sparse z
    float* __restrict__ sel_val,
    int*   __restrict__ sel_idx)
{
    __shared__ unsigned hist[256];
    __shared__ unsigned gsfx[65];
    __shared__ unsigned sfx[257];
    __shared__ int      sdelta;
    __shared__ unsigned scnt;
    __shared__ int      l_idx[K_];
    __shared__ float    l_val[K_];
    __shared__ int      eq_min;

    const int t = threadIdx.x;
    const int b = blockIdx.x;
    float* zrow = z + (size_t)b * DSAE;

    float v[16]; unsigned u[16];
    #pragma unroll
    for (int i = 0; i < 16; ++i) {
        float f = zrow[t + (i << 10)];
        v[i] = f;
        unsigned xb = __float_as_uint(f);
        u[i] = (xb & 0x80000000u) ? ~xb : (xb | 0x80000000u);
    }

    unsigned prefix = 0, pmask = 0;
    int need = K_;

    for (int p = 0; p < 4; ++p) {
        const int shift = 24 - 8 * p;
        if (t < 256) hist[t] = 0;
        __syncthreads();
        #pragma unroll
        for (int i = 0; i < 16; ++i)
            if ((u[i] & pmask) == prefix)
                atomicAdd(&hist[(u[i] >> shift) & 255u], 1u);
        __syncthreads();
        if (t < 64) {
            unsigned s4 = hist[4*t] + hist[4*t+1] + hist[4*t+2] + hist[4*t+3];
            #pragma unroll
            for (int off = 1; off < 64; off <<= 1) {
                unsigned o = __shfl_down(s4, off, 64);
                if (t + off < 64) s4 += o;
            }
            gsfx[t] = s4;
            if (t == 0) gsfx[64] = 0;
        }
        __syncthreads();
        if (t < 256) {
            int q = t >> 2;
            unsigned acc = gsfx[q + 1];
            for (int d = 4*q + 3; d >= t; --d) acc += hist[d];
            sfx[t] = acc;
            if (t == 0) sfx[256] = 0;
        }
        __syncthreads();
        if (t < 256) {
            if (sfx[t] >= (unsigned)need && sfx[t + 1] < (unsigned)need) sdelta = t;
        }
        __syncthreads();
        const int dlt = sdelta;
        need  -= (int)sfx[dlt + 1];
        prefix |= ((unsigned)dlt) << shift;
        pmask  |= 0xFFu << shift;
        __syncthreads();
    }

    const unsigned ustar = prefix;
    if (t == 0) scnt = 0;
    __syncthreads();

    unsigned eqmask = 0;
    #pragma unroll
    for (int i = 0; i < 16; ++i) {
        int idx = t + (i << 10);
        if (u[i] > ustar) {
            unsigned s = atomicAdd(&scnt, 1u);
            l_idx[s] = idx; l_val[s] = v[i];
        } else if (u[i] == ustar) {
            eqmask |= (1u << i);
        }
    }
    __syncthreads();
    const int needf = need;
    for (int r = 0; r < needf; ++r) {
        if (t == 0) eq_min = 0x7FFFFFFF;
        __syncthreads();
        #pragma unroll
        for (int i = 0; i < 16; ++i)
            if (eqmask & (1u << i)) atomicMin(&eq_min, t + (i << 10));
        __syncthreads();
        #pragma unroll
        for (int i = 0; i < 16; ++i)
            if ((eqmask & (1u << i)) && (t + (i << 10) == eq_min)) {
                eqmask &= ~(1u << i);
                unsigned s = atomicAdd(&scnt, 1u);
                l_idx[s] = eq_min; l_val[s] = v[i];
            }
        __syncthreads();
    }

    #pragma unroll
    for (int i = 0; i < 16; ++i) zrow[t + (i << 10)] = 0.f;
    __syncthreads();
    if (t == 0) {
        for (int a = 1; a < K_; ++a) {
            int ia = l_idx[a]; float va = l_val[a]; int c = a - 1;
            while (c >= 0 && l_idx[c] > ia) {
                l_idx[c+1] = l_idx[c]; l_val[c+1] = l_val[c]; --c;
            }
            l_idx[c+1] = ia; l_val[c+1] = va;
        }
    }
    __syncthreads();
    if (t < K_) {
        float val = l_val[t] > 0.f ? l_val[t] : 0.f;
        zrow[l_idx[t]] = val;
        sel_val[(b << 5) + t] = val;
        sel_idx[(b << 5) + t] = l_idx[t];
    }
}

// ---------------- Kernel 5: sparse decode + fused sq-err, atomic loss ----------------
__global__ __launch_bounds__(256, 4) void decode_kernel(
    const float* __restrict__ W_dec,
    const float* __restrict__ b_dec,
    const float* __restrict__ x,
    const float* __restrict__ sel_val,
    const int*   __restrict__ sel_idx,
    float* __restrict__ xhat,          // d_out + 1
    float* __restrict__ out0)
{
    __shared__ float sv[K_];
    __shared__ int   si[K_];
    __shared__ float wsum[4];

    const int t     = threadIdx.x;
    const int blk   = blockIdx.x;
    const int b     = blk / 12;
    const int chunk = blk - b * 12;

    if (t < K_) { sv[t] = sel_val[(b << 5) + t]; si[t] = sel_idx[(b << 5) + t]; }
    __syncthreads();

    const int e = chunk * 1024 + t * 4;
    float4 acc = *(const float4*)&b_dec[e];
    #pragma unroll 8
    for (int j = 0; j < K_; ++j) {
        const float val = sv[j];
        const float4 wd = *(const float4*)&W_dec[(size_t)si[j] * TD + e];
        acc.x += val * wd.x;
        acc.y += val * wd.y;
        acc.z += val * wd.z;
        acc.w += val * wd.w;
    }

    const size_t xo = (size_t)b * TD + e;
    xhat[xo + 0] = acc.x;
    xhat[xo + 1] = acc.y;
    xhat[xo + 2] = acc.z;
    xhat[xo + 3] = acc.w;

    const float4 xv = *(const float4*)&x[xo];
    float dx = acc.x - xv.x, dy = acc.y - xv.y;
    float dz = acc.z - xv.z, dw = acc.w - xv.w;
    float ss = dx * dx + dy * dy + dz * dz + dw * dw;
    #pragma unroll
    for (int off = 32; off > 0; off >>= 1) ss += __shfl_down(ss, off, 64);
    if ((t & 63) == 0) wsum[t >> 6] = ss;
    __syncthreads();
    if (t == 0)
        atomicAdd(out0, (wsum[0] + wsum[1] + wsum[2] + wsum[3]) * (1.0f / 512.0f));
}

extern "C" void kernel_launch(void* const* d_in, const int* in_sizes, int n_in,
                              void* d_out, int out_size, void* d_ws, size_t ws_size,
                              hipStream_t stream) {
    const float* x      = (const float*)d_in[0];
    const float* conv_w = (const float*)d_in[1];
    const float* b_enc  = (const float*)d_in[2];
    const float* W_dec  = (const float*)d_in[3];
    const float* b_dec  = (const float*)d_in[4];

    float* out  = (float*)d_out;
    float* xhat = out + 1;                        // (32,16,768)
    float* z    = out + 1 + 393216;               // (32,16384) — holds pre then sparse z

    float* partial_enc = (float*)d_ws;                          // 16.8 MB
    float* A_T         = (float*)((char*)d_ws + (20u << 20));   // 288 KB
    float* sel_val     = (float*)((char*)d_ws + (21u << 20));
    int*   sel_idx     = (int*)  ((char*)d_ws + (21u << 20) + 4096);

    prep_kernel    <<<96,  256,  0, stream>>>(x, A_T);
    enc_gemm_kernel<<<512, 256,  0, stream>>>(conv_w, A_T, partial_enc);
    combine_kernel <<<512, 256,  0, stream>>>(partial_enc, b_enc, z, out);
    topk_kernel    <<<32,  1024, 0, stream>>>(z, sel_val, sel_idx);
    decode_kernel  <<<384, 256,  0, stream>>>(W_dec, b_dec, x, sel_val, sel_idx, xhat, out);
}